// Round 2
// baseline (1411.599 us; speedup 1.0000x reference)
//
#include <hip/hip_runtime.h>
#include <cstdint>

#define NODE_DIM 256
#define HALF 128
#define NJ 17

typedef __bf16 bf16x8 __attribute__((ext_vector_type(8)));
typedef float f32x4 __attribute__((ext_vector_type(4)));

// round-to-nearest-even fp32 -> bf16 bits
__device__ __forceinline__ unsigned short f2bf(float f) {
  unsigned int u = __builtin_bit_cast(unsigned int, f);
  u = (u + 0x7FFFu + ((u >> 16) & 1u)) >> 16;
  return (unsigned short)u;
}

__device__ __forceinline__ unsigned int pack2(float lo, float hi) {
  return (unsigned int)f2bf(lo) | ((unsigned int)f2bf(hi) << 16);
}

// async global->LDS, 16B per lane, LDS dest = wave-uniform base + lane*16
__device__ __forceinline__ void gload16(const void* g, void* l) {
  __builtin_amdgcn_global_load_lds(
      (const __attribute__((address_space(1))) unsigned int*)g,
      (__attribute__((address_space(3))) unsigned int*)l, 16, 0, 0);
}

// layer-1 pair joints (groups 1..6), layer-2 pair groups
__device__ const int d_P0[6] = {5, 7, 8, 11, 13, 14};
__device__ const int d_P1[6] = {6, 9, 10, 12, 15, 16};
__device__ const int d_Q0[6] = {0, 1, 1, 1, 4, 4};
__device__ const int d_Q1[6] = {1, 2, 3, 4, 5, 6};

// ---------------------------------------------------------------------------
// Kernel 0: convert the four weight matrices fp32 -> bf16 into ws
// segments: W1_0 163840 | W1 393216 | W2 196608 | Wf 196608  (total 950272)
// ---------------------------------------------------------------------------
__global__ __launch_bounds__(256) void kconv(
    const float* __restrict__ a, const float* __restrict__ b,
    const float* __restrict__ c, const float* __restrict__ d,
    unsigned short* __restrict__ dst) {
  const int na = 163840, nb = 393216, nc = 196608, nd = 196608;
  const int total = na + nb + nc + nd;
  int i = (blockIdx.x * 256 + threadIdx.x) * 4;
  if (i >= total) return;
  const float* src;
  int off;
  if (i < na) { src = a; off = i; }
  else if (i < na + nb) { src = b; off = i - na; }
  else if (i < na + nb + nc) { src = c; off = i - na - nb; }
  else { src = d; off = i - na - nb - nc; }
  float4 v = *(const float4*)(src + off);
  uint2 p;
  p.x = pack2(v.x, v.y);
  p.y = pack2(v.z, v.w);
  *(uint2*)(dst + i) = p;
}

// ===========================================================================
// Shared GEMM shape:
//   64-node x Ncols output tile, K-chunks of 64.
//   LDS rows 64 shorts (128 B), XOR-swizzle byte_in_row ^= ((row&7)<<4) on
//   BOTH store-source and read (linear gload_lds dest + inverse-swizzled
//   global source).  Single __syncthreads per chunk (implicit vmcnt(0)
//   drain completes async stages), double-buffered.
//   k1/k2: one block per 64-node tile, internal loop over groups (sequential
//   update read, L2-hot out1 re-reads).  k3: full 256-col tile, acc[16].
// ===========================================================================

// ---------------------------------------------------------------------------
// Kernel 1: layer 1.  grid = ntiles, block = 256.  Internal g-loop 0..6.
// group 0: K=1280 (joints 0..4), groups 1..6: K=512 (joint pairs).
// A fp32 -> reg-stage + pack (swizzled ds_write); W via gload_lds.
// out1[n][g][128] bf16 via LDS-transpose epilogue (64B stores).
// ---------------------------------------------------------------------------
__global__ __launch_bounds__(256) void k1_layer1(
    const float* __restrict__ upd,
    const unsigned short* __restrict__ w10,
    const unsigned short* __restrict__ w1,
    const float* __restrict__ b10,
    const float* __restrict__ b1,
    unsigned short* __restrict__ out1,
    int N) {
  __shared__ unsigned short sA[2][64 * 64];    // 2 x 8 KiB
  __shared__ unsigned short sW[2][128 * 64];   // 2 x 16 KiB

  const int t = threadIdx.x;
  const int lane = t & 63;
  const int wv = t >> 6;
  const int l16 = lane & 15;
  const int quad = lane >> 4;
  const int node0 = blockIdx.x * 64;

  const int ar = t >> 2, al = t & 3;
  int an = node0 + ar;
  if (an >= N) an = N - 1;

  const int lrow = lane >> 3;
  const int sg = ((lane & 7) ^ lrow) << 3;

  for (int g = 0; g < 7; ++g) {
    const int K = (g == 0) ? 1280 : 512;
    const unsigned short* W = (g == 0) ? w10 : (w1 + (size_t)(g - 1) * 128 * 512);
    const int pj0 = (g == 0) ? 0 : d_P0[g - 1];
    const int pj1 = (g == 0) ? 0 : d_P1[g - 1];
    const int nch = K >> 6;

    f32x4 acc[8];
#pragma unroll
    for (int i = 0; i < 8; ++i) acc[i] = (f32x4){0.f, 0.f, 0.f, 0.f};

    __syncthreads();  // fence prev g's epilogue reads vs this g's staging

    float4 f0, f1, f2, f3;
    {  // prologue: stage chunk 0
#pragma unroll
      for (int i = 0; i < 4; ++i) {
        int c = wv * 4 + i;
        int row = c * 8 + lrow;
        gload16(W + (size_t)row * K + sg, &sW[0][c * 512]);
      }
      const int j0 = (g == 0) ? 0 : pj0;
      const float* src = upd + ((size_t)an * NJ + j0) * NODE_DIM + al * 16;
      f0 = *(const float4*)(src);
      f1 = *(const float4*)(src + 4);
      f2 = *(const float4*)(src + 8);
      f3 = *(const float4*)(src + 12);
    }

    int buf = 0;
    for (int kc = 0; kc < nch; ++kc) {
      {  // pack A(kc) -> sA[buf] (swizzled)
        uint4 pa0, pa1;
        pa0.x = pack2(f0.x, f0.y); pa0.y = pack2(f0.z, f0.w);
        pa0.z = pack2(f1.x, f1.y); pa0.w = pack2(f1.z, f1.w);
        pa1.x = pack2(f2.x, f2.y); pa1.y = pack2(f2.z, f2.w);
        pa1.z = pack2(f3.x, f3.y); pa1.w = pack2(f3.z, f3.w);
        const int sw0 = (al * 32) ^ ((ar & 7) << 4);
        *(uint4*)(&sA[buf][ar * 64 + (sw0 >> 1)]) = pa0;
        *(uint4*)(&sA[buf][ar * 64 + ((sw0 ^ 16) >> 1)]) = pa1;
      }
      __syncthreads();  // drains W(kc) gload_lds + A ds_writes

      if (kc + 1 < nch) {
        const int kabs = (kc + 1) << 6;
#pragma unroll
        for (int i = 0; i < 4; ++i) {
          int c = wv * 4 + i;
          int row = c * 8 + lrow;
          gload16(W + (size_t)row * K + kabs + sg, &sW[buf ^ 1][c * 512]);
        }
        const int j = (g == 0) ? (kabs >> 8) : ((kabs < 256) ? pj0 : pj1);
        const float* src = upd + ((size_t)an * NJ + j) * NODE_DIM + (kabs & 255) + al * 16;
        f0 = *(const float4*)(src);
        f1 = *(const float4*)(src + 4);
        f2 = *(const float4*)(src + 8);
        f3 = *(const float4*)(src + 12);
      }

#pragma unroll
      for (int kk = 0; kk < 2; ++kk) {
        const int k2 = kk * 64 + quad * 16;
        const int ksw = ((k2 ^ ((l16 & 7) << 4)) >> 1);
        const int arow = wv * 16 + l16;
        bf16x8 a = *(const bf16x8*)(&sA[buf][arow * 64 + ksw]);
#pragma unroll
        for (int nt = 0; nt < 8; ++nt) {
          const int brow = nt * 16 + l16;
          bf16x8 b = *(const bf16x8*)(&sW[buf][brow * 64 + ksw]);
          acc[nt] = __builtin_amdgcn_mfma_f32_16x16x32_bf16(a, b, acc[nt], 0, 0, 0);
        }
      }
      buf ^= 1;
    }

    // epilogue: bias+relu, LDS transpose (pad 136), 64B coalesced stores
    __syncthreads();
    unsigned short* tr = &sW[0][0];  // 8704 shorts used; 16384 available
    const float* bias = (g == 0) ? b10 : (b1 + (g - 1) * HALF);
#pragma unroll
    for (int nt = 0; nt < 8; ++nt) {
      const float bv = bias[nt * 16 + l16];
#pragma unroll
      for (int r = 0; r < 4; ++r) {
        const int node = wv * 16 + quad * 4 + r;
        float v = acc[nt][r] + bv;
        v = v > 0.f ? v : 0.f;
        tr[node * 136 + nt * 16 + l16] = f2bf(v);
      }
    }
    __syncthreads();
    {
      const int nodeL = t >> 2, part = t & 3;
      const int gn = node0 + nodeL;
      if (gn < N) {
        const uint4* s = (const uint4*)(tr + nodeL * 136 + part * 32);
        uint4* d = (uint4*)(out1 + (size_t)gn * 896 + g * 128 + part * 32);
        d[0] = s[0]; d[1] = s[1]; d[2] = s[2]; d[3] = s[3];
      }
    }
  }
}

// ---------------------------------------------------------------------------
// Kernel 2: layer 2.  grid = ntiles, internal g-loop 0..5.  K=256 pair gather
// from out1 (repeat reads of groups 1/4 become L2 hits within the block).
// ---------------------------------------------------------------------------
__global__ __launch_bounds__(256) void k2_layer2(
    const unsigned short* __restrict__ out1,
    const unsigned short* __restrict__ w2,
    const float* __restrict__ b2,
    unsigned short* __restrict__ out2,
    int N) {
  __shared__ unsigned short sA[2][64 * 64];
  __shared__ unsigned short sW[2][128 * 64];

  const int t = threadIdx.x;
  const int lane = t & 63;
  const int wv = t >> 6;
  const int l16 = lane & 15;
  const int quad = lane >> 4;
  const int node0 = blockIdx.x * 64;

  const int lrow = lane >> 3;
  const int sg = ((lane & 7) ^ lrow) << 3;

  for (int g = 0; g < 6; ++g) {
    const unsigned short* W = w2 + (size_t)g * 128 * 256;
    const int p0 = d_Q0[g], p1 = d_Q1[g];

    f32x4 acc[8];
#pragma unroll
    for (int i = 0; i < 8; ++i) acc[i] = (f32x4){0.f, 0.f, 0.f, 0.f};

    auto stage = [&](int b, int kc) {
      const int kabs = kc << 6;
      const int grp = (kabs < 128) ? p0 : p1;
      const int kin = kabs & 127;
#pragma unroll
      for (int i = 0; i < 2; ++i) {
        int c = wv * 2 + i;
        int row = c * 8 + lrow;
        int gn = node0 + row; if (gn >= N) gn = N - 1;
        gload16(out1 + (size_t)gn * 896 + grp * 128 + kin + sg, &sA[b][c * 512]);
      }
#pragma unroll
      for (int i = 0; i < 4; ++i) {
        int c = wv * 4 + i;
        int row = c * 8 + lrow;
        gload16(W + row * 256 + kabs + sg, &sW[b][c * 512]);
      }
    };

    __syncthreads();  // fence prev g's epilogue reads vs this g's staging
    stage(0, 0);
    int buf = 0;
    for (int kc = 0; kc < 4; ++kc) {
      __syncthreads();
      if (kc + 1 < 4) stage(buf ^ 1, kc + 1);
#pragma unroll
      for (int kk = 0; kk < 2; ++kk) {
        const int k2 = kk * 64 + quad * 16;
        const int ksw = ((k2 ^ ((l16 & 7) << 4)) >> 1);
        const int arow = wv * 16 + l16;
        bf16x8 a = *(const bf16x8*)(&sA[buf][arow * 64 + ksw]);
#pragma unroll
        for (int nt = 0; nt < 8; ++nt) {
          const int brow = nt * 16 + l16;
          bf16x8 b = *(const bf16x8*)(&sW[buf][brow * 64 + ksw]);
          acc[nt] = __builtin_amdgcn_mfma_f32_16x16x32_bf16(a, b, acc[nt], 0, 0, 0);
        }
      }
      buf ^= 1;
    }

    __syncthreads();
    unsigned short* tr = &sW[0][0];
    const float* bias = b2 + g * HALF;
#pragma unroll
    for (int nt = 0; nt < 8; ++nt) {
      const float bv = bias[nt * 16 + l16];
#pragma unroll
      for (int r = 0; r < 4; ++r) {
        const int node = wv * 16 + quad * 4 + r;
        float v = acc[nt][r] + bv;
        v = v > 0.f ? v : 0.f;
        tr[node * 136 + nt * 16 + l16] = f2bf(v);
      }
    }
    __syncthreads();
    {
      const int nodeL = t >> 2, part = t & 3;
      const int gn = node0 + nodeL;
      if (gn < N) {
        const uint4* s = (const uint4*)(tr + nodeL * 136 + part * 32);
        uint4* d = (uint4*)(out2 + (size_t)gn * 768 + g * 128 + part * 32);
        d[0] = s[0]; d[1] = s[1]; d[2] = s[2]; d[3] = s[3];
      }
    }
  }
}

// ---------------------------------------------------------------------------
// Kernel 3: final.  grid = ntiles.  Full 256 cols (acc[16]), K=768, out2
// read ONCE.  LDS 80 KiB -> 2 blocks/CU.
// ---------------------------------------------------------------------------
__global__ __launch_bounds__(256) void k3_final(
    const unsigned short* __restrict__ out2,
    const unsigned short* __restrict__ wf,
    const float* __restrict__ bf_,
    float* __restrict__ out,
    int N) {
  __shared__ unsigned short sA[2][64 * 64];    // 16 KiB
  __shared__ unsigned short sW[2][256 * 64];   // 64 KiB

  const int t = threadIdx.x;
  const int lane = t & 63;
  const int wv = t >> 6;
  const int l16 = lane & 15;
  const int quad = lane >> 4;
  const int node0 = blockIdx.x * 64;

  const int lrow = lane >> 3;
  const int sg = ((lane & 7) ^ lrow) << 3;

  f32x4 acc[16];
#pragma unroll
  for (int i = 0; i < 16; ++i) acc[i] = (f32x4){0.f, 0.f, 0.f, 0.f};

  auto stage = [&](int b, int kc) {
    const int kabs = kc << 6;
#pragma unroll
    for (int i = 0; i < 2; ++i) {
      int c = wv * 2 + i;
      int row = c * 8 + lrow;
      int gn = node0 + row; if (gn >= N) gn = N - 1;
      gload16(out2 + (size_t)gn * 768 + kabs + sg, &sA[b][c * 512]);
    }
#pragma unroll
    for (int i = 0; i < 8; ++i) {
      int c = wv * 8 + i;
      int row = c * 8 + lrow;
      gload16(wf + (size_t)row * 768 + kabs + sg, &sW[b][c * 512]);
    }
  };

  stage(0, 0);
  int buf = 0;
  for (int kc = 0; kc < 12; ++kc) {
    __syncthreads();
    if (kc + 1 < 12) stage(buf ^ 1, kc + 1);
#pragma unroll
    for (int kk = 0; kk < 2; ++kk) {
      const int k2 = kk * 64 + quad * 16;
      const int ksw = ((k2 ^ ((l16 & 7) << 4)) >> 1);
      const int arow = wv * 16 + l16;
      bf16x8 a = *(const bf16x8*)(&sA[buf][arow * 64 + ksw]);
#pragma unroll
      for (int nt = 0; nt < 16; ++nt) {
        const int brow = nt * 16 + l16;
        bf16x8 b = *(const bf16x8*)(&sW[buf][brow * 64 + ksw]);
        acc[nt] = __builtin_amdgcn_mfma_f32_16x16x32_bf16(a, b, acc[nt], 0, 0, 0);
      }
    }
    buf ^= 1;
  }

#pragma unroll
  for (int nt = 0; nt < 16; ++nt) {
    const float bv = bf_[nt * 16 + l16];
#pragma unroll
    for (int r = 0; r < 4; ++r) {
      const int node = node0 + wv * 16 + quad * 4 + r;
      if (node < N) {
        float v = acc[nt][r] + bv;
        v = v > 0.f ? v : 0.f;
        out[(size_t)node * 256 + nt * 16 + l16] = v;
      }
    }
  }
}

// ---------------------------------------------------------------------------
extern "C" void kernel_launch(void* const* d_in, const int* in_sizes, int n_in,
                              void* d_out, int out_size, void* d_ws, size_t ws_size,
                              hipStream_t stream) {
  const float* upd = (const float*)d_in[0];
  const float* W10f = (const float*)d_in[1];
  const float* b10 = (const float*)d_in[2];
  const float* W1f = (const float*)d_in[3];
  const float* b1 = (const float*)d_in[4];
  const float* W2f = (const float*)d_in[5];
  const float* b2 = (const float*)d_in[6];
  const float* Wff = (const float*)d_in[7];
  const float* bff = (const float*)d_in[8];

  const int N = in_sizes[0] / (NJ * NODE_DIM);
  const int ntiles = (N + 63) / 64;

  unsigned short* wbf = (unsigned short*)d_ws;
  unsigned short* w10 = wbf;
  unsigned short* w1 = wbf + 163840;
  unsigned short* w2 = wbf + 163840 + 393216;
  unsigned short* wf = wbf + 163840 + 393216 + 196608;
  unsigned short* out1 = (unsigned short*)((char*)d_ws + (size_t)(2u << 20));
  unsigned short* out2 = out1 + (size_t)N * 896;

  // weights: 950272 elems / 4 per thread = 237568 threads
  kconv<<<(237568 + 255) / 256, 256, 0, stream>>>(W10f, W1f, W2f, Wff, wbf);
  k1_layer1<<<ntiles, 256, 0, stream>>>(upd, w10, w1, b10, b1, out1, N);
  k2_layer2<<<ntiles, 256, 0, stream>>>(out1, w2, b2, out2, N);
  k3_final<<<ntiles, 256, 0, stream>>>(out2, wf, bff, (float*)d_out, N);
}